// Round 1
// baseline (536.031 us; speedup 1.0000x reference)
//
#include <hip/hip_runtime.h>
#include <math.h>

// LorentzNotGroupNorm on MI355X.
// x: (64, 56*56, 128) fp32, groups=8 -> group = 8 consecutive pixels x 128 ch.
// One wave (64 lanes) per group; lane l owns channels {2l, 2l+1} (float2).
// Pass 1: accumulate sum_s ||x_T|| into var_acc[b*8+p] (512 floats in d_ws).
// Pass 2: recompute x_T (x is L3-resident after pass 1), normalize, transp0,
// expmap, write out.

__device__ __forceinline__ float wave_sum(float v) {
#pragma unroll
  for (int m = 32; m >= 1; m >>= 1) v += __shfl_xor(v, m, 64);
  return v;
}

struct Grp {
  float yx[8], yy[8];  // this lane's two channels for each of 8 pixels
  float mx, my;        // centroid (this lane's two channels)
  float mean0;         // centroid time component (broadcast)
  float s0;            // -1 on lane 0 (channel 0 = time), else +1
};

__device__ __forceinline__ void load_and_mean(const float* __restrict__ gp,
                                              int lane, Grp& g) {
  float ax = 0.f, ay = 0.f;
#pragma unroll
  for (int p = 0; p < 8; ++p) {
    const float2 v = *reinterpret_cast<const float2*>(gp + p * 128 + 2 * lane);
    g.yx[p] = v.x;
    g.yy[p] = v.y;
    ax += v.x;
    ay += v.y;
  }
  ax *= 0.125f;
  ay *= 0.125f;
  g.s0 = (lane == 0) ? -1.f : 1.f;
  // l_inner(avg, avg) = -avg0^2 + sum_{i>=1} avg_i^2
  float ia = wave_sum(g.s0 * ax * ax + ay * ay);
  float rden = rsqrtf(fmaxf(-ia, 1e-8f));
  g.mx = ax * rden;
  g.my = ay * rden;
  g.mean0 = __shfl(g.mx, 0, 64);
}

// logmap(mean, y_p) followed by transp0back(mean, .) -> tangent at origin
__device__ __forceinline__ void compute_xt(const Grp& g, int p, int lane,
                                           float& ox, float& oy) {
  float dot = wave_sum(g.s0 * g.mx * g.yx[p] + g.my * g.yy[p]);  // <mean,y>_L
  float alpha = fmaxf(-dot, 1.f + 1e-7f);
  float t = alpha - 1.f;
  float dist = log1pf(t + sqrtf(t * (alpha + 1.f)));  // arccosh(alpha)
  float nx = g.yx[p] - alpha * g.mx;
  float ny = g.yy[p] - alpha * g.my;
  float inn = wave_sum(g.s0 * nx * nx + ny * ny);  // l_inner(nomin, nomin)
  float sc = dist * rsqrtf(fmaxf(inn, 1e-8f));
  float xtx = nx * sc;
  float xty = ny * sc;
  // transp0back: v + (-v0/(1+mean0)) * (mean + origin)
  float xt0 = __shfl(xtx, 0, 64);
  float coef = -xt0 / (1.f + g.mean0);
  xtx += coef * (g.mx + ((lane == 0) ? 1.f : 0.f));
  xty += coef * g.my;
  ox = xtx;
  oy = xty;
}

__global__ __launch_bounds__(256) void lngn_pass1(const float* __restrict__ x,
                                                  float* __restrict__ var_acc,
                                                  int n_groups, int S) {
  int wid = (int)((blockIdx.x * blockDim.x + threadIdx.x) >> 6);
  int lane = threadIdx.x & 63;
  if (wid >= n_groups) return;
  Grp g;
  load_and_mean(x + (size_t)wid * 1024, lane, g);
  int b = wid / S;
#pragma unroll
  for (int p = 0; p < 8; ++p) {
    float xtx, xty;
    compute_xt(g, p, lane, xtx, xty);
    float nsq = wave_sum(xtx * xtx + xty * xty);  // Euclidean norm^2
    if (lane == 0) atomicAdd(var_acc + b * 8 + p, sqrtf(nsq));
  }
}

__global__ __launch_bounds__(256) void lngn_pass2(
    const float* __restrict__ x, const float* __restrict__ gamma,
    const float* __restrict__ beta, const float* __restrict__ var_acc,
    float* __restrict__ out, int n_groups, int S, float invS) {
  int wid = (int)((blockIdx.x * blockDim.x + threadIdx.x) >> 6);
  int lane = threadIdx.x & 63;
  if (wid >= n_groups) return;
  Grp g;
  const size_t base = (size_t)wid * 1024;
  load_and_mean(x + base, lane, g);
  int b = wid / S;
  const float2 gm = *reinterpret_cast<const float2*>(gamma + 2 * lane);
  const float2 bt = *reinterpret_cast<const float2*>(beta + 2 * lane);
  float beta0 = __shfl(bt.x, 0, 64);
#pragma unroll
  for (int p = 0; p < 8; ++p) {
    float xtx, xty;
    compute_xt(g, p, lane, xtx, xty);
    // x_T * gamma / (var + eps)
    float var = var_acc[b * 8 + p] * invS;
    float s1 = 1.f / (var + 1e-5f);
    float ux = xtx * gm.x * s1;
    float uy = xty * gm.y * s1;
    // rescale_to_max_euclid
    float nsq = wave_sum(ux * ux + uy * uy);
    float n = sqrtf(nsq);
    float sc2 = fminf(1.f, 10.f / fmaxf(n, 1e-8f));
    ux *= sc2;
    uy *= sc2;
    // transp0(beta, u): u + (<beta,u>_L / (1+beta0)) * (beta + origin)
    float nom = wave_sum(g.s0 * bt.x * ux + bt.y * uy);
    float c2 = nom / (1.f + beta0);
    ux += c2 * (bt.x + ((lane == 0) ? 1.f : 0.f));
    uy += c2 * bt.y;
    // expmap(beta, u): cosh(nrm)*beta + sinh(nrm)*u/nrm
    float inn = wave_sum(g.s0 * ux * ux + uy * uy);
    float nrm = sqrtf(fmaxf(inn, 1e-8f));
    float e = expf(nrm);
    float ie = 1.f / e;
    float ch = 0.5f * (e + ie);
    float isn = (0.5f * (e - ie)) / nrm;
    float2 o;
    o.x = ch * bt.x + isn * ux;
    o.y = ch * bt.y + isn * uy;
    *reinterpret_cast<float2*>(out + base + p * 128 + 2 * lane) = o;
  }
}

extern "C" void kernel_launch(void* const* d_in, const int* in_sizes, int n_in,
                              void* d_out, int out_size, void* d_ws,
                              size_t ws_size, hipStream_t stream) {
  const float* x = (const float*)d_in[0];
  const float* gamma = (const float*)d_in[1];
  const float* beta = (const float*)d_in[2];
  float* out = (float*)d_out;
  float* var_acc = (float*)d_ws;

  const int BS = 64, HW = 56 * 56, G = 8;
  const int S = HW / G;           // 392 spatial groups per batch
  const int n_groups = BS * S;    // 25088 waves of work

  hipMemsetAsync(var_acc, 0, (size_t)BS * G * sizeof(float), stream);

  dim3 blk(256);  // 4 waves/block, one group per wave
  dim3 grid((n_groups + 3) / 4);
  lngn_pass1<<<grid, blk, 0, stream>>>(x, var_acc, n_groups, S);
  lngn_pass2<<<grid, blk, 0, stream>>>(x, gamma, beta, var_acc, out, n_groups,
                                       S, 1.f / (float)S);
}

// Round 2
// 229.299 us; speedup vs baseline: 2.3377x; 2.3377x over previous
//
#include <hip/hip_runtime.h>
#include <math.h>

// LorentzNotGroupNorm on MI355X (gfx950), x:(64,3136,128) fp32, groups=8.
// Group = 8 consecutive pixels x 128 channels = 4KB. One wave per group.
// Layout: lane = 8*p + q  (p = pixel 0..7, q = channel block 0..7, each lane
// owns channels [16q,16q+16) of its pixel as 4x float4).
// All channel reductions: 3-stage xor{1,2,4} butterfly within the 8 q-lanes,
// vectorized across the 8 pixels. Pixel-mean: fold-butterfly over lane bits
// {32,16,8} (14 shuffles) + LDS redistribute.

constexpr int S_GROUPS = 392;          // spatial groups per batch (3136/8)
constexpr int NSL = 16;                // var accumulation slices
constexpr int N_GROUPS = 64 * S_GROUPS;

__device__ __forceinline__ float rsum8(float v) {
  v += __shfl_xor(v, 1, 64);
  v += __shfl_xor(v, 2, 64);
  v += __shfl_xor(v, 4, 64);
  return v;
}

// Loads one group's pixel/channels for this lane and computes x_T (tangent at
// origin, transp0back applied). v[16] = raw values, xt[16] = x_T.
__device__ __forceinline__ void lorentz_xt(const float* __restrict__ gp,
                                           int lane, float* __restrict__ smrow,
                                           float v[16], float xt[16]) {
  const int p = lane >> 3, q = lane & 7;
  const float* base = gp + p * 128 + q * 16;
#pragma unroll
  for (int j = 0; j < 4; ++j)
    *reinterpret_cast<float4*>(&v[4 * j]) =
        *reinterpret_cast<const float4*>(base + 4 * j);

  // ---- mean over 8 pixels: fold over lane bits 5,4,3 ----
  float a8[8];
  {
    const bool hi = (lane & 32) != 0;
#pragma unroll
    for (int i = 0; i < 8; ++i) {
      float kp = hi ? v[i + 8] : v[i];
      float sd = hi ? v[i] : v[i + 8];
      a8[i] = kp + __shfl_xor(sd, 32, 64);
    }
  }
  float a4[4];
  {
    const bool hi = (lane & 16) != 0;
#pragma unroll
    for (int i = 0; i < 4; ++i) {
      float kp = hi ? a8[i + 4] : a8[i];
      float sd = hi ? a8[i] : a8[i + 4];
      a4[i] = kp + __shfl_xor(sd, 16, 64);
    }
  }
  float c0, c1;
  {
    const bool hi = (lane & 8) != 0;
    float kp0 = hi ? a4[2] : a4[0], sd0 = hi ? a4[0] : a4[2];
    float kp1 = hi ? a4[3] : a4[1], sd1 = hi ? a4[1] : a4[3];
    c0 = kp0 + __shfl_xor(sd0, 8, 64);
    c1 = kp1 + __shfl_xor(sd1, 8, 64);
  }
  // lane (p,q) holds pixel-summed channels {16q+2p, 16q+2p+1}
  *reinterpret_cast<float2*>(&smrow[q * 16 + p * 2]) =
      make_float2(c0 * 0.125f, c1 * 0.125f);
  __syncthreads();
  float mean[16];
#pragma unroll
  for (int j = 0; j < 4; ++j)
    *reinterpret_cast<float4*>(&mean[4 * j]) =
        *reinterpret_cast<const float4*>(&smrow[q * 16 + 4 * j]);

  // ia = <avg,avg>_L (group-wide scalar, replicated per pixel-row)
  float part = 0.f;
#pragma unroll
  for (int i = 0; i < 16; ++i) part += mean[i] * mean[i];
  if (q == 0) part -= 2.f * mean[0] * mean[0];
  float ia = rsum8(part);
  float rden = rsqrtf(fmaxf(-ia, 1e-8f));
#pragma unroll
  for (int i = 0; i < 16; ++i) mean[i] *= rden;  // centroid on hyperboloid
  float mean0 = __shfl(mean[0], 0, 64);          // channel-0 of centroid
  float y0p = __shfl(v[0], lane & 56, 64);       // y_p[0] broadcast in row

  // logmap(mean, y_p): alpha = -<mean,y>_L
  float dp = 0.f;
#pragma unroll
  for (int i = 0; i < 16; ++i) dp += mean[i] * v[i];
  if (q == 0) dp -= 2.f * mean[0] * v[0];
  dp = rsum8(dp);
  float alpha = fmaxf(-dp, 1.f + 1e-7f);
  float t = alpha - 1.f;
  float dist = log1pf(t + sqrtf(t * (alpha + 1.f)));  // arccosh(alpha)

  float nm[16];
  float ip = 0.f;
#pragma unroll
  for (int i = 0; i < 16; ++i) {
    nm[i] = v[i] - alpha * mean[i];
    ip += nm[i] * nm[i];
  }
  if (q == 0) ip -= 2.f * nm[0] * nm[0];
  float inn = rsum8(ip);
  float sc = dist * rsqrtf(fmaxf(inn, 1e-8f));

  // transp0back: x_T = sc*nm + coef*(mean + e0), coef = -xt0/(1+mean0)
  float xt0 = sc * (y0p - alpha * mean0);
  float coef = -xt0 / (1.f + mean0);
#pragma unroll
  for (int i = 0; i < 16; ++i) xt[i] = sc * nm[i] + coef * mean[i];
  if (q == 0) xt[0] += coef;
}

__global__ __launch_bounds__(256) void lngn_pass1(const float* __restrict__ x,
                                                  float* __restrict__ var_acc) {
  __shared__ float sm[4][128];
  const int w = threadIdx.x >> 6;
  const int lane = threadIdx.x & 63;
  const int wid = blockIdx.x * 4 + w;
  float v[16], xt[16];
  lorentz_xt(x + (size_t)wid * 1024, lane, sm[w], v, xt);
  float ns = 0.f;
#pragma unroll
  for (int i = 0; i < 16; ++i) ns += xt[i] * xt[i];
  ns = rsum8(ns);
  const int p = lane >> 3, q = lane & 7;
  if (q == 0) {
    int b = wid / S_GROUPS;
    atomicAdd(&var_acc[(b * 8 + p) * NSL + (wid & (NSL - 1))], sqrtf(ns));
  }
}

__global__ __launch_bounds__(256) void lngn_finalize(
    const float* __restrict__ var_acc, float* __restrict__ var_out) {
  int i = blockIdx.x * 256 + threadIdx.x;  // 0..511
  float s = 0.f;
#pragma unroll
  for (int j = 0; j < NSL; ++j) s += var_acc[i * NSL + j];
  var_out[i] = s * (1.f / (float)S_GROUPS);
}

__global__ __launch_bounds__(256) void lngn_pass2(
    const float* __restrict__ x, const float* __restrict__ gamma,
    const float* __restrict__ beta, const float* __restrict__ var,
    float* __restrict__ out) {
  __shared__ float sm[4][128];
  const int w = threadIdx.x >> 6;
  const int lane = threadIdx.x & 63;
  const int wid = blockIdx.x * 4 + w;
  const int p = lane >> 3, q = lane & 7;
  float v[16], xt[16];
  lorentz_xt(x + (size_t)wid * 1024, lane, sm[w], v, xt);

  const int b = wid / S_GROUPS;
  float s1 = 1.f / (var[b * 8 + p] + 1e-5f);

  float gm[16];
#pragma unroll
  for (int j = 0; j < 4; ++j)
    *reinterpret_cast<float4*>(&gm[4 * j]) =
        *reinterpret_cast<const float4*>(gamma + q * 16 + 4 * j);
  float u[16];
  float nsq = 0.f;
#pragma unroll
  for (int i = 0; i < 16; ++i) {
    u[i] = xt[i] * gm[i] * s1;
    nsq += u[i] * u[i];
  }
  nsq = rsum8(nsq);  // Euclidean norm^2 over all 128 channels
  float n = sqrtf(nsq);
  float scl = fminf(1.f, 10.f / fmaxf(n, 1e-8f));

  float bt[16];
#pragma unroll
  for (int j = 0; j < 4; ++j)
    *reinterpret_cast<float4*>(&bt[4 * j]) =
        *reinterpret_cast<const float4*>(beta + q * 16 + 4 * j);
  float beta0 = __shfl(bt[0], 0, 64);

  // transp0(beta, u)
  float np = 0.f;
#pragma unroll
  for (int i = 0; i < 16; ++i) {
    u[i] *= scl;
    np += bt[i] * u[i];
  }
  if (q == 0) np -= 2.f * bt[0] * u[0];
  float nom = rsum8(np);
  float c2 = nom / (1.f + beta0);
  float ip = 0.f;
#pragma unroll
  for (int i = 0; i < 16; ++i) {
    u[i] += c2 * bt[i];
    ip += u[i] * u[i];
  }
  if (q == 0) {
    u[0] += c2;
    ip -= 2.f * (u[0] - c2) * (u[0] - c2);   // redo sign for updated u[0]
    ip += u[0] * u[0] - (u[0] - c2) * (u[0] - c2);
    ip -= 2.f * u[0] * u[0] + 2.f * (u[0] - c2) * (u[0] - c2) -
          2.f * (u[0] - c2) * (u[0] - c2);
  }
  // The above in-place sign fix is error-prone; recompute cleanly:
  ip = 0.f;
#pragma unroll
  for (int i = 0; i < 16; ++i) ip += u[i] * u[i];
  if (q == 0) ip -= 2.f * u[0] * u[0];
  float inn = rsum8(ip);

  // expmap(beta, u)
  float nrm = sqrtf(fmaxf(inn, 1e-8f));
  float e = expf(nrm), ie = 1.f / e;
  float chv = 0.5f * (e + ie);
  float isn = (0.5f * (e - ie)) / nrm;
  float o[16];
#pragma unroll
  for (int i = 0; i < 16; ++i) o[i] = chv * bt[i] + isn * u[i];
  float* ob = out + (size_t)wid * 1024 + p * 128 + q * 16;
#pragma unroll
  for (int j = 0; j < 4; ++j)
    *reinterpret_cast<float4*>(ob + 4 * j) =
        *reinterpret_cast<const float4*>(&o[4 * j]);
}

extern "C" void kernel_launch(void* const* d_in, const int* in_sizes, int n_in,
                              void* d_out, int out_size, void* d_ws,
                              size_t ws_size, hipStream_t stream) {
  const float* x = (const float*)d_in[0];
  const float* gamma = (const float*)d_in[1];
  const float* beta = (const float*)d_in[2];
  float* out = (float*)d_out;
  float* var_acc = (float*)d_ws;               // 512 * NSL floats
  float* var_final = var_acc + 512 * NSL;      // 512 floats

  hipMemsetAsync(var_acc, 0, 512 * NSL * sizeof(float), stream);
  lngn_pass1<<<N_GROUPS / 4, 256, 0, stream>>>(x, var_acc);
  lngn_finalize<<<2, 256, 0, stream>>>(var_acc, var_final);
  lngn_pass2<<<N_GROUPS / 4, 256, 0, stream>>>(x, gamma, beta, var_final, out);
}

// Round 3
// 224.357 us; speedup vs baseline: 2.3892x; 1.0220x over previous
//
#include <hip/hip_runtime.h>
#include <math.h>

// LorentzNotGroupNorm, MI355X. x:(64,3136,128) fp32, groups=8.
// Group = 8 consecutive pixels x 128 ch = 4KB; one wave per group.
// lane = 8*p + q: pixel p (0..7), channel block q (0..7), 16 ch/lane (4xfloat4).
// Algebraic collapse: with m = avg*rden (so <m,m>_L = -1):
//   alpha_raw = -<avg,y>_L * rden;  alpha = max(alpha_raw, 1+1e-7)
//   <nomin,nomin>_L = <y,y>_L + 2*alpha*alpha_raw - alpha^2
//   x_T = sc*y + k*avg + coef*e0   (scalars sc,k,coef per pixel)
// so each pass needs only the fold (pixel mean) + ONE joint 3-chain rsum8.

constexpr int S_GROUPS = 392;              // spatial groups per batch
constexpr int N_GROUPS = 64 * S_GROUPS;    // 25088

__device__ __forceinline__ void wave_lds_fence() {
  // Intra-wave LDS producer->consumer: block store-forwarding and reordering.
  __asm__ volatile("" ::: "memory");
  __builtin_amdgcn_wave_barrier();
  __asm__ volatile("" ::: "memory");
}

__device__ __forceinline__ void rsum8x3(float& a, float& b, float& c) {
#pragma unroll
  for (int m = 1; m <= 4; m <<= 1) {
    a += __shfl_xor(a, m, 64);
    b += __shfl_xor(b, m, 64);
    c += __shfl_xor(c, m, 64);
  }
}

// Pixel-mean fold over lane bits {32,16,8}; lane (p,q) ends with mean
// channels {16q+2p, 16q+2p+1} in (c0,c1).
__device__ __forceinline__ void fold_mean(const float v[16], int lane,
                                          float& c0, float& c1) {
  float a8[8];
  const bool h5 = (lane & 32) != 0;
#pragma unroll
  for (int i = 0; i < 8; ++i) {
    float kp = h5 ? v[i + 8] : v[i];
    float sd = h5 ? v[i] : v[i + 8];
    a8[i] = kp + __shfl_xor(sd, 32, 64);
  }
  float a4[4];
  const bool h4 = (lane & 16) != 0;
#pragma unroll
  for (int i = 0; i < 4; ++i) {
    float kp = h4 ? a8[i + 4] : a8[i];
    float sd = h4 ? a8[i] : a8[i + 4];
    a4[i] = kp + __shfl_xor(sd, 16, 64);
  }
  const bool h3 = (lane & 8) != 0;
  float kp0 = h3 ? a4[2] : a4[0], sd0 = h3 ? a4[0] : a4[2];
  float kp1 = h3 ? a4[3] : a4[1], sd1 = h3 ? a4[1] : a4[3];
  c0 = (kp0 + __shfl_xor(sd0, 8, 64)) * 0.125f;
  c1 = (kp1 + __shfl_xor(sd1, 8, 64)) * 0.125f;
}

struct CoreOut {
  float avg[16];                       // unnormalized pixel-mean (this lane's 16 ch)
  float sc, k, coef;                   // x_T = sc*y + k*avg + coef*e0
  float iaL, dpL, yyE, y0p, avg0;      // reduced scalars (dpL,yyE per pixel-row)
};

__device__ __forceinline__ void core(const float v[16], int lane,
                                     float* __restrict__ smrow, CoreOut& o) {
  const int p = lane >> 3, q = lane & 7;
  float c0, c1;
  fold_mean(v, lane, c0, c1);
  *reinterpret_cast<float2*>(&smrow[q * 16 + p * 2]) = make_float2(c0, c1);
  wave_lds_fence();
#pragma unroll
  for (int j = 0; j < 4; ++j)
    *reinterpret_cast<float4*>(&o.avg[4 * j]) =
        *reinterpret_cast<const float4*>(&smrow[q * 16 + 4 * j]);
  wave_lds_fence();

  float pa = 0.f, pd = 0.f, py = 0.f;
#pragma unroll
  for (int i = 0; i < 16; ++i) {
    pa = fmaf(o.avg[i], o.avg[i], pa);   // -> <avg,avg>_L
    pd = fmaf(o.avg[i], v[i], pd);       // -> <avg,y>_L
    py = fmaf(v[i], v[i], py);           // -> ||y||^2_E
  }
  if (q == 0) {
    pa -= 2.f * o.avg[0] * o.avg[0];
    pd -= 2.f * o.avg[0] * v[0];
  }
  rsum8x3(pa, pd, py);
  o.iaL = pa;
  o.dpL = pd;
  o.yyE = py;
  o.y0p = __shfl(v[0], lane & 56, 64);     // y_p[0]
  o.avg0 = __shfl(o.avg[0], 0, 64);        // avg channel 0

  float rden = rsqrtf(fmaxf(-pa, 1e-8f));
  float a_raw = -pd * rden;
  float alpha = fmaxf(a_raw, 1.f + 1e-7f);
  float t = alpha - 1.f;
  float dist = log1pf(t + sqrtf(t * (alpha + 1.f)));    // arccosh(alpha)
  float yyL = py - 2.f * o.y0p * o.y0p;                 // <y,y>_L
  float inn = fmaxf(yyL + 2.f * alpha * a_raw - alpha * alpha, 1e-8f);
  o.sc = dist * rsqrtf(inn);
  float am = alpha * rden;
  float mean0 = rden * o.avg0;
  float v0 = o.sc * (o.y0p - am * o.avg0);              // x_T time comp pre-transp
  o.coef = -v0 / (1.f + mean0);
  o.k = o.coef * rden - o.sc * am;
}

__device__ __forceinline__ float xt_norm(const CoreOut& A) {
  // ||x_T||_E from scalars: x_T = sc*y + k*avg + coef*e0
  float yavgE = A.dpL + 2.f * A.avg0 * A.y0p;
  float aaE = A.iaL + 2.f * A.avg0 * A.avg0;
  float nsq = A.sc * A.sc * A.yyE + A.k * A.k * aaE + 2.f * A.sc * A.k * yavgE +
              A.coef * A.coef + 2.f * A.coef * (A.sc * A.y0p + A.k * A.avg0);
  return sqrtf(fmaxf(nsq, 0.f));
}

__global__ __launch_bounds__(256) void lngn_pass1(const float* __restrict__ x,
                                                  float* __restrict__ var_part) {
  __shared__ float sm[4][2][128];
  const int w = threadIdx.x >> 6, lane = threadIdx.x & 63;
  const int p = lane >> 3, q = lane & 7;
  const int wid0 = (blockIdx.x * 4 + w) * 2;   // 2 groups per wave
  const float* b0 = x + (size_t)wid0 * 1024 + p * 128 + q * 16;
  float vA[16], vB[16];
#pragma unroll
  for (int j = 0; j < 4; ++j) {
    *reinterpret_cast<float4*>(&vA[4 * j]) =
        *reinterpret_cast<const float4*>(b0 + 4 * j);
    *reinterpret_cast<float4*>(&vB[4 * j]) =
        *reinterpret_cast<const float4*>(b0 + 1024 + 4 * j);
  }
  CoreOut A, B;
  core(vA, lane, sm[w][0], A);
  core(vB, lane, sm[w][1], B);
  float nA = xt_norm(A), nB = xt_norm(B);
  if (q == 0) {
    var_part[(size_t)wid0 * 8 + p] = nA;
    var_part[(size_t)(wid0 + 1) * 8 + p] = nB;
  }
}

__global__ __launch_bounds__(256) void lngn_finalize(
    const float* __restrict__ var_part, float* __restrict__ var_out) {
  const int wv = (int)((blockIdx.x * 256 + threadIdx.x) >> 6);  // 0..511
  const int lane = threadIdx.x & 63;
  const int b = wv >> 3, p = wv & 7;
  const float* base = var_part + (size_t)b * S_GROUPS * 8 + p;
  float s = 0.f;
  for (int s0 = lane; s0 < S_GROUPS; s0 += 64) s += base[(size_t)s0 * 8];
#pragma unroll
  for (int m = 32; m >= 1; m >>= 1) s += __shfl_xor(s, m, 64);
  if (lane == 0) var_out[wv] = s * (1.f / (float)S_GROUPS);
}

__global__ __launch_bounds__(256) void lngn_pass2(
    const float* __restrict__ x, const float* __restrict__ gamma,
    const float* __restrict__ beta, const float* __restrict__ var,
    float* __restrict__ out) {
  __shared__ float sm[4][128];
  const int w = threadIdx.x >> 6, lane = threadIdx.x & 63;
  const int p = lane >> 3, q = lane & 7;
  const int wid = blockIdx.x * 4 + w;
  const size_t base = (size_t)wid * 1024 + p * 128 + q * 16;
  float v[16];
#pragma unroll
  for (int j = 0; j < 4; ++j)
    *reinterpret_cast<float4*>(&v[4 * j]) =
        *reinterpret_cast<const float4*>(x + base + 4 * j);
  CoreOut C;
  core(v, lane, sm[w], C);

  const int b = wid / S_GROUPS;
  const float s1 = 1.f / (var[b * 8 + p] + 1e-5f);
  float gm[16], bt[16];
#pragma unroll
  for (int j = 0; j < 4; ++j) {
    *reinterpret_cast<float4*>(&gm[4 * j]) =
        *reinterpret_cast<const float4*>(gamma + q * 16 + 4 * j);
    *reinterpret_cast<float4*>(&bt[4 * j]) =
        *reinterpret_cast<const float4*>(beta + q * 16 + 4 * j);
  }

  float u[16];
  float pe = 0.f, pb = 0.f, pbb = 0.f;
#pragma unroll
  for (int i = 0; i < 16; ++i) {
    float xt = fmaf(C.sc, v[i], C.k * C.avg[i]);
    if (i == 0) xt += (q == 0) ? C.coef : 0.f;
    u[i] = xt * (gm[i] * s1);
    pe = fmaf(u[i], u[i], pe);          // ||u||^2_E
    pb = fmaf(bt[i], u[i], pb);         // -> <beta,u>_L
    pbb = fmaf(bt[i], bt[i], pbb);      // -> <beta,beta>_L
  }
  if (q == 0) {
    pb -= 2.f * bt[0] * u[0];
    pbb -= 2.f * bt[0] * bt[0];
  }
  rsum8x3(pe, pb, pbb);
  const float u0 = __shfl(u[0], 0, 64);
  const float bt0 = __shfl(bt[0], 0, 64);

  float n = sqrtf(pe);
  float scl = fminf(1.f, 10.f / fmaxf(n, 1e-8f));   // rescale_to_max_euclid
  float c2 = scl * pb / (1.f + bt0);                // transp0 coefficient
  float uuL = pe - 2.f * u0 * u0;                   // <u,u>_L
  // w = scl*u + c2*(beta+e0); <w,w>_L expanded in scalars:
  float innw = scl * scl * uuL + 2.f * scl * c2 * (pb - u0) +
               c2 * c2 * (pbb - 2.f * bt0 - 1.f);
  float nrm = sqrtf(fmaxf(innw, 1e-8f));
  float e = expf(nrm), ie = 1.f / e;
  float chv = 0.5f * (e + ie);
  float isn = (0.5f * (e - ie)) / nrm;
  // out = chv*beta + isn*w = (chv+isn*c2)*beta + (isn*scl)*u + (isn*c2)*e0
  float C1 = chv + isn * c2, C2 = isn * scl, C3 = isn * c2;
  float o16[16];
#pragma unroll
  for (int i = 0; i < 16; ++i) o16[i] = fmaf(C1, bt[i], C2 * u[i]);
  if (q == 0) o16[0] += C3;
  float* ob = out + base;
#pragma unroll
  for (int j = 0; j < 4; ++j)
    *reinterpret_cast<float4*>(ob + 4 * j) =
        *reinterpret_cast<const float4*>(&o16[4 * j]);
}

extern "C" void kernel_launch(void* const* d_in, const int* in_sizes, int n_in,
                              void* d_out, int out_size, void* d_ws,
                              size_t ws_size, hipStream_t stream) {
  const float* x = (const float*)d_in[0];
  const float* gamma = (const float*)d_in[1];
  const float* beta = (const float*)d_in[2];
  float* out = (float*)d_out;
  float* var_part = (float*)d_ws;                 // 25088*8 floats (802816 B)
  float* var_final = var_part + (size_t)N_GROUPS * 8;  // 512 floats

  lngn_pass1<<<N_GROUPS / 8, 256, 0, stream>>>(x, var_part);      // 3136 blocks
  lngn_finalize<<<128, 256, 0, stream>>>(var_part, var_final);    // 512 waves
  lngn_pass2<<<N_GROUPS / 4, 256, 0, stream>>>(x, gamma, beta, var_final, out);
}